// Round 5
// baseline (233.104 us; speedup 1.0000x reference)
//
#include <hip/hip_runtime.h>

// Faster-RCNN box-head postprocess, 3 regular dispatches (round-0 skeleton:
// every device-scope-sync alternative measured 45-65us slower on gfx950).
// Bound used: M100 = 100th-largest per-row max key <= T (100th-largest entry),
// so a threshold from the P row-max keys lower-bounds T; rows with
// maxk >= lb contain the whole top-100. Candidates >= lb are refined with an
// entry-level 12-bit threshold, then ranked by counting (rank = #{keys > me}
// over unique keys == descending-sort position; bit-identical to a full sort).
// R5 change: both 12-bit thresholds are found by register-resident BINARY
// SEARCH (12 iters of count>=mid + block reduce) instead of a 4096-bucket
// LDS-atomic histogram + suffix scan. Identical result (largest bucket b with
// count(keys >= b) >= target), no atomics, no 16KB hist, no zeroing passes.
// K1: per-row softmax offset + max fg score key (1 expf for the key, monotone).
// K2: binsearch lb -> hot rows -> collect -> binsearch lb2 -> compact ->
//     rank-by-count -> box decode.
// K3: parallel feature gather.
#define NCLS 91
#define NFG 90
#define NDET 100
#define FDIM 1024
#define CAP 4096
#define BBOX_CLIP 4.135166556742356f
#define K1_TPB 256
#define RPB 32             // rows per K1 block (8 per wave)
#define K2_TPB 1024

// ---------------- K1: softmax offset + per-row max fg key ----------------
__global__ __launch_bounds__(K1_TPB) void k1_soft(
        const float* __restrict__ logits, float* __restrict__ rowoff,
        unsigned* __restrict__ maxk, int N) {
    int wave = threadIdx.x >> 6, lane = threadIdx.x & 63;
    int rowbase = blockIdx.x * RPB + wave * (RPB / 4);
    for (int it = 0; it < RPB / 4; it++) {
        long long row = rowbase + it;
        if (row >= N) return;
        const float* r = logits + row * NCLS;
        float l1 = r[lane];                              // classes 0..63
        float l2 = (lane < NCLS - 64) ? r[64 + lane] : -INFINITY;  // 64..90
        // fg max first; global max = fmax(fg max, class-0 logit)
        float mf = fmaxf((lane == 0) ? -INFINITY : l1, l2);
        #pragma unroll
        for (int o = 32; o; o >>= 1) mf = fmaxf(mf, __shfl_xor(mf, o));
        float m = fmaxf(mf, __shfl(l1, 0));              // bitwise same as full max
        float e = expf(l1 - m) + ((lane < NCLS - 64) ? expf(l2 - m) : 0.0f);
        #pragma unroll
        for (int o = 32; o; o >>= 1) e += __shfl_xor(e, o);
        float off = m + logf(e);                         // same bits all lanes
        // expf monotone => key of max fg logit == max over fg entry keys
        unsigned km = __float_as_uint(expf(mf - off));
        if (lane == 0) { rowoff[row] = off; maxk[row] = km; }
    }
}

// Register-resident binary-search threshold: returns the largest 12-bit
// bucket b (0..4095) with count(v >= b) >= target, where each thread holds
// MV bucket values in registers (invalid slots = 0: they only inflate the
// count at b==0, which binary search never tests and whose result is
// unaffected). Identical semantics to the old histogram+suffix-scan
// find_threshold. All threads must call; all return the same b.
template<int MV>
__device__ __forceinline__ unsigned bin_thresh(const unsigned (&v)[MV],
                                               unsigned* rsum, unsigned* sh_cnt,
                                               int tid, unsigned target) {
    const int lane = tid & 63, wave = tid >> 6;
    int lo = 0, hi = 4095;
    while (lo < hi) {
        int mid = (lo + hi + 1) >> 1;
        unsigned c = 0;
        #pragma unroll
        for (int k = 0; k < MV; k++) c += (v[k] >= (unsigned)mid) ? 1u : 0u;
        #pragma unroll
        for (int o = 32; o; o >>= 1) c += __shfl_xor(c, o);
        if (lane == 0) rsum[wave] = c;
        __syncthreads();
        if (tid == 0) {
            unsigned s = 0;
            #pragma unroll
            for (int w = 0; w < (K2_TPB >> 6); w++) s += rsum[w];
            *sh_cnt = s;
        }
        __syncthreads();
        if (*sh_cnt >= target) lo = mid; else hi = mid - 1;
    }
    return (unsigned)lo;
}

// ---------------- K2: per-image select + box decode ----------------
__global__ __launch_bounds__(K2_TPB) void k2_select(
        const float* __restrict__ logits, const float* __restrict__ reg,
        const float* __restrict__ props,
        const int* __restrict__ pH, const int* __restrict__ pW,
        const float* __restrict__ rowoff, const unsigned* __restrict__ maxk,
        float* __restrict__ outBoxes, unsigned* __restrict__ keepRow, int P) {
    __shared__ unsigned long long cand[CAP];    // 32 KB
    __shared__ unsigned long long cbuf[2048];   // 16 KB; also hot-row u32[4096]
    __shared__ unsigned long long win[NDET];    // 800 B ranked winners
    __shared__ unsigned rsum[K2_TPB >> 6];
    __shared__ unsigned sh_cnt, sh_nhot, sh_ncand, sh_n2;

    const int img = blockIdx.x;
    const int tid = threadIdx.x;
    const unsigned* mk = maxk + (size_t)img * P;
    unsigned* hot = (unsigned*)cbuf;

    if (tid == 0) { sh_nhot = 0; sh_ncand = 0; sh_n2 = 0; }

    // --- per-thread row-max buckets (top 12 key bits) into registers ---
    unsigned bk[8];                              // supports P <= 8192
    #pragma unroll
    for (int k = 0; k < 8; k++) {
        int r = tid + k * K2_TPB;
        bk[k] = (r < P) ? (mk[r] >> 20) : 0u;
    }
    __syncthreads();

    // --- lb_row: largest bucket with count(row-max >= bucket) >= NDET ---
    unsigned lbb = bin_thresh<8>(bk, rsum, &sh_cnt, tid, NDET);
    const unsigned lb = lbb << 20;      // lb <= M100 <= T
    const unsigned lbh = lb ? lb - 1 : 0;   // 1-ulp slack for maxk monotonicity

    // --- hot rows: maxk >= lb-1 (superset of rows feeding the top-100) ---
    for (int r = tid; r < P; r += K2_TPB)
        if (mk[r] >= lbh) hot[atomicAdd(&sh_nhot, 1u)] = (unsigned)r;
    __syncthreads();
    const int nhot = (int)sh_nhot;

    // --- collect entries >= lb from hot rows (wave per row) ---
    const int wave = tid >> 6, lane = tid & 63;
    for (int i = wave; i < nhot; i += K2_TPB / 64) {
        int rl = (int)hot[i];
        long long row = (long long)img * P + rl;
        float off = rowoff[row];
        const float* r = logits + row * NCLS;
        float l1 = r[lane];
        float l2 = (lane < NCLS - 64) ? r[64 + lane] : -INFINITY;
        if (lane >= 1) {
            unsigned k = __float_as_uint(expf(l1 - off));
            if (k >= lb) {
                unsigned pos = atomicAdd(&sh_ncand, 1u);
                if (pos < CAP)
                    cand[pos] = ((unsigned long long)k << 32) |
                                (unsigned)(0xFFFFFFFFu - (unsigned)(rl * NFG + lane - 1));
            }
        }
        if (lane < NCLS - 64) {
            unsigned k = __float_as_uint(expf(l2 - off));
            if (k >= lb) {
                unsigned pos = atomicAdd(&sh_ncand, 1u);
                if (pos < CAP)
                    cand[pos] = ((unsigned long long)k << 32) |
                                (unsigned)(0xFFFFFFFFu - (unsigned)(rl * NFG + 63 + lane));
            }
        }
    }
    __syncthreads();
    unsigned cnt = sh_ncand; if (cnt > CAP) cnt = CAP;

    const unsigned long long* pool = cand;
    unsigned pcnt = cnt;                // >= NDET (each hot row's max >= lb)

    if (cnt > 128) {
        // --- entry-level refinement: threshold over candidate key top bits ---
        unsigned ek[4];                          // cnt <= CAP = 4*K2_TPB
        #pragma unroll
        for (int k = 0; k < 4; k++) {
            unsigned i = (unsigned)tid + k * K2_TPB;
            ek[k] = (i < cnt) ? (unsigned)(cand[i] >> 52) : 0u;
        }
        __syncthreads();
        unsigned b2 = bin_thresh<4>(ek, rsum, &sh_cnt, tid, NDET);
        unsigned lb2 = b2 << 20;        // lb2 >= lb, count(keys >= lb2) >= NDET
        // --- compact keys >= lb2 into cbuf ---
        for (int i = tid; i < (int)cnt; i += K2_TPB) {
            unsigned long long k64 = cand[i];
            if ((unsigned)(k64 >> 32) >= lb2) {
                unsigned pos = atomicAdd(&sh_n2, 1u);
                if (pos < 2048) cbuf[pos] = k64;
            }
        }
        __syncthreads();
        unsigned cnt2 = sh_n2;
        if (cnt2 <= 2048) { pool = cbuf; pcnt = cnt2; }  // expected path
        // else: pathological tie storm; rank over the full cand set (correct,
        // just slower) — pool/pcnt already set.
    }

    // --- rank-by-count: rank = #{keys > me}; unique keys => rank == position
    //     in the descending sort (bit-identical to a full sort's output).
    //     Wave per candidate; lanes stride the pool (conflict-free reads). ---
    for (unsigned i = wave; i < pcnt; i += K2_TPB / 64) {
        unsigned long long me = pool[i];
        unsigned ng = 0;
        for (unsigned j = lane; j < pcnt; j += 64)
            ng += (pool[j] > me) ? 1u : 0u;
        #pragma unroll
        for (int o = 32; o; o >>= 1) ng += __shfl_xor(ng, o);
        if (lane == 0 && ng < NDET) win[ng] = me;
    }
    __syncthreads();

    // --- decode + clip + normalize top-100 boxes; record feature rows ---
    if (tid < NDET) {
        unsigned long long key = win[tid];
        unsigned e = 0xFFFFFFFFu - (unsigned)(key & 0xFFFFFFFFull);
        int pr = e / NFG, cm = e - pr * NFG, c = cm + 1;
        long long rw = (long long)img * P + pr;
        float x1 = props[rw * 4 + 0], y1 = props[rw * 4 + 1];
        float x2 = props[rw * 4 + 2], y2 = props[rw * 4 + 3];
        float w = x2 - x1, hgt = y2 - y1;
        float cx = x1 + 0.5f * w, cy = y1 + 0.5f * hgt;
        const float* rr = reg + rw * (4 * NCLS) + 4 * c;
        float dx = rr[0] / 10.0f, dy = rr[1] / 10.0f;
        float dw = fminf(rr[2] / 5.0f, BBOX_CLIP);
        float dh = fminf(rr[3] / 5.0f, BBOX_CLIP);
        float pcx = dx * w + cx, pcy = dy * hgt + cy;
        float pw_ = expf(dw) * w, ph_ = expf(dh) * hgt;
        float bx1 = pcx - 0.5f * pw_, by1 = pcy - 0.5f * ph_;
        float bx2 = pcx + 0.5f * pw_, by2 = pcy + 0.5f * ph_;
        float W = (float)(*pW), H = (float)(*pH);
        bx1 = fminf(fmaxf(bx1, 0.0f), W);
        bx2 = fminf(fmaxf(bx2, 0.0f), W);
        by1 = fminf(fmaxf(by1, 0.0f), H);
        by2 = fminf(fmaxf(by2, 0.0f), H);
        int o = (img * NDET + tid) * 4;
        outBoxes[o + 0] = bx1 / H;
        outBoxes[o + 1] = by1 / H;
        outBoxes[o + 2] = bx2 / H;
        outBoxes[o + 3] = by2 / H;
        keepRow[img * NDET + tid] = (unsigned)rw;
    }
}

// ---------------- K3: feature gather (1 det per block, float4) ----------------
__global__ __launch_bounds__(256) void k3_feats(
        const float* __restrict__ feats, const unsigned* __restrict__ keepRow,
        float* __restrict__ outF) {
    int det = blockIdx.x;
    long long r = keepRow[det];
    const float4* src = (const float4*)(feats + r * FDIM);
    float4* dst = (float4*)(outF + (long long)det * FDIM);
    dst[threadIdx.x] = src[threadIdx.x];
}

extern "C" void kernel_launch(void* const* d_in, const int* in_sizes, int n_in,
                              void* d_out, int out_size, void* d_ws, size_t ws_size,
                              hipStream_t stream) {
    const float* logits = (const float*)d_in[0];
    const float* reg    = (const float*)d_in[1];
    const float* props  = (const float*)d_in[2];
    const float* feats  = (const float*)d_in[3];
    const int*   pH     = (const int*)d_in[5];
    const int*   pW     = (const int*)d_in[6];

    int N = in_sizes[0] / NCLS;               // total proposals (B*P)
    int B = out_size / (NDET * (4 + FDIM));   // 8
    int P = N / B;

    // workspace: rowoff [N] f32 | maxk [N] u32 | keepRow [B*NDET] u32
    char* ws = (char*)d_ws;
    float*    rowoff  = (float*)ws;
    unsigned* maxk    = (unsigned*)(rowoff + N);
    unsigned* keepRow = (unsigned*)(maxk + N);

    float* outBoxes = (float*)d_out;
    float* outFeats = outBoxes + (size_t)B * NDET * 4;

    k1_soft<<<(N + RPB - 1) / RPB, K1_TPB, 0, stream>>>(logits, rowoff, maxk, N);
    k2_select<<<B, K2_TPB, 0, stream>>>(logits, reg, props, pH, pW,
                                        rowoff, maxk, outBoxes, keepRow, P);
    k3_feats<<<B * NDET, 256, 0, stream>>>(feats, keepRow, outFeats);
}

// Round 6
// 224.839 us; speedup vs baseline: 1.0368x; 1.0368x over previous
//
#include <hip/hip_runtime.h>
#include <hip/hip_bf16.h>

// Faster-RCNN box-head postprocess, 3 regular dispatches.
// Bound used: M100 = 100th-largest per-row max key <= T (100th-largest entry),
// so a threshold from the P row-max keys lower-bounds T; rows with
// maxk >= lb contain the whole top-100. Candidates >= lb are then refined with
// an entry-level 12-bit histogram to shrink the final bitonic sort.
// K1: per-row softmax offset + max fg score key (1 expf for the key, monotone).
// K2: row-max hist -> lb_row -> hot rows -> collect -> entry hist -> lb_ent ->
//     compact -> bitonic sort -> box decode.
// K3: parallel feature gather.
// [R6 note: byte-identical revert to the best-measured variant (R0, 223.6us).
//  R1 distributed-atomics +42, R2 cooperative +66, R3 last-block +50,
//  R4 ballot-hist/rank +8, R5 binsearch/rank +9.5 -- all regressions or
//  within-noise; harness fills at 85% HBM peak dominate the timed window.]
#define NCLS 91
#define NFG 90
#define NDET 100
#define FDIM 1024
#define CAP 4096
#define NBUK 4096
#define BBOX_CLIP 4.135166556742356f
#define K1_TPB 256
#define RPB 32             // rows per K1 block (8 per wave)
#define K2_TPB 1024

// ---------------- K1: softmax offset + per-row max fg key ----------------
__global__ __launch_bounds__(K1_TPB) void k1_soft(
        const float* __restrict__ logits, float* __restrict__ rowoff,
        unsigned* __restrict__ maxk, int N) {
    int wave = threadIdx.x >> 6, lane = threadIdx.x & 63;
    int rowbase = blockIdx.x * RPB + wave * (RPB / 4);
    for (int it = 0; it < RPB / 4; it++) {
        long long row = rowbase + it;
        if (row >= N) return;
        const float* r = logits + row * NCLS;
        float l1 = r[lane];                              // classes 0..63
        float l2 = (lane < NCLS - 64) ? r[64 + lane] : -INFINITY;  // 64..90
        // fg max first; global max = fmax(fg max, class-0 logit)
        float mf = fmaxf((lane == 0) ? -INFINITY : l1, l2);
        #pragma unroll
        for (int o = 32; o; o >>= 1) mf = fmaxf(mf, __shfl_xor(mf, o));
        float m = fmaxf(mf, __shfl(l1, 0));              // bitwise same as full max
        float e = expf(l1 - m) + ((lane < NCLS - 64) ? expf(l2 - m) : 0.0f);
        #pragma unroll
        for (int o = 32; o; o >>= 1) e += __shfl_xor(e, o);
        float off = m + logf(e);                         // same bits all lanes
        // expf monotone => key of max fg logit == max over fg entry keys
        unsigned km = __float_as_uint(expf(mf - off));
        if (lane == 0) { rowoff[row] = off; maxk[row] = km; }
    }
}

// Parallel suffix-scan threshold finder over a 4096-bucket LDS histogram.
// tid<256 threads own 16 buckets each; finds lb = floor of highest bucket b
// where count(keys >= b) crosses `target` from above. All threads must call.
__device__ __forceinline__ void find_threshold(const unsigned* hist,
                                               unsigned* wsum, unsigned* sh_lb,
                                               int tid, unsigned target) {
    unsigned local[16]; unsigned s = 0, run = 0;
    if (tid < 256) {
        #pragma unroll
        for (int i = 0; i < 16; i++) { local[i] = hist[tid * 16 + i]; s += local[i]; }
        run = s;
        #pragma unroll
        for (int off = 1; off < 64; off <<= 1) {     // in-wave inclusive suffix
            unsigned v = __shfl_down(run, off);
            if ((tid & 63) + off < 64) run += v;
        }
        if ((tid & 63) == 0) wsum[tid >> 6] = run;   // 4 wave totals
    }
    __syncthreads();
    if (tid < 256) {
        int w = tid >> 6;
        #pragma unroll
        for (int ww = 0; ww < 4; ww++) if (ww > w) run += wsum[ww];
        unsigned above = run - s;                    // strictly above my chunk
        #pragma unroll
        for (int i = 15; i >= 0; i--) {
            unsigned prev = above; above += local[i];
            if (above >= target && prev < target)
                *sh_lb = ((unsigned)(tid * 16 + i)) << 20;
        }
    }
    __syncthreads();
}

// ---------------- K2: per-image select + box decode ----------------
__global__ __launch_bounds__(K2_TPB) void k2_select(
        const float* __restrict__ logits, const float* __restrict__ reg,
        const float* __restrict__ props,
        const int* __restrict__ pH, const int* __restrict__ pW,
        const float* __restrict__ rowoff, const unsigned* __restrict__ maxk,
        float* __restrict__ outBoxes, unsigned* __restrict__ keepRow, int P) {
    __shared__ unsigned long long cand[CAP];    // 32 KB
    __shared__ unsigned long long cbuf[2048];   // 16 KB; also hot-row u32[4096]
    __shared__ unsigned hist[NBUK];             // 16 KB
    __shared__ unsigned wsum[4];
    __shared__ unsigned sh_lb, sh_lb2, sh_nhot, sh_ncand, sh_n2;

    const int img = blockIdx.x;
    const int tid = threadIdx.x;
    const unsigned* mk = maxk + (size_t)img * P;
    unsigned* hot = (unsigned*)cbuf;

    if (tid == 0) { sh_nhot = 0; sh_ncand = 0; sh_n2 = 0; sh_lb = 0; sh_lb2 = 0; }
    for (int b = tid; b < NBUK; b += K2_TPB) hist[b] = 0u;
    __syncthreads();

    // --- row-max histogram (top 12 key bits) -> lb_row ---
    for (int r = tid; r < P; r += K2_TPB) atomicAdd(&hist[mk[r] >> 20], 1u);
    __syncthreads();
    find_threshold(hist, wsum, &sh_lb, tid, NDET);
    const unsigned lb = sh_lb;          // lb <= M100 <= T
    const unsigned lbh = lb ? lb - 1 : 0;   // 1-ulp slack for maxk monotonicity

    // --- hot rows: maxk >= lb-1 (superset of rows feeding the top-100) ---
    for (int r = tid; r < P; r += K2_TPB)
        if (mk[r] >= lbh) hot[atomicAdd(&sh_nhot, 1u)] = (unsigned)r;
    __syncthreads();
    const int nhot = (int)sh_nhot;

    // --- collect entries >= lb from hot rows (wave per row) ---
    const int wave = tid >> 6, lane = tid & 63;
    for (int i = wave; i < nhot; i += K2_TPB / 64) {
        int rl = (int)hot[i];
        long long row = (long long)img * P + rl;
        float off = rowoff[row];
        const float* r = logits + row * NCLS;
        float l1 = r[lane];
        float l2 = (lane < NCLS - 64) ? r[64 + lane] : -INFINITY;
        if (lane >= 1) {
            unsigned k = __float_as_uint(expf(l1 - off));
            if (k >= lb) {
                unsigned pos = atomicAdd(&sh_ncand, 1u);
                if (pos < CAP)
                    cand[pos] = ((unsigned long long)k << 32) |
                                (unsigned)(0xFFFFFFFFu - (unsigned)(rl * NFG + lane - 1));
            }
        }
        if (lane < NCLS - 64) {
            unsigned k = __float_as_uint(expf(l2 - off));
            if (k >= lb) {
                unsigned pos = atomicAdd(&sh_ncand, 1u);
                if (pos < CAP)
                    cand[pos] = ((unsigned long long)k << 32) |
                                (unsigned)(0xFFFFFFFFu - (unsigned)(rl * NFG + 63 + lane));
            }
        }
    }
    __syncthreads();
    unsigned cnt = sh_ncand; if (cnt > CAP) cnt = CAP;
    int n;

    if (cnt > 128) {
        // --- entry-level refinement: 12-bit hist of candidate keys -> lb_ent ---
        for (int b = tid; b < NBUK; b += K2_TPB) hist[b] = 0u;
        __syncthreads();
        for (int i = tid; i < (int)cnt; i += K2_TPB)
            atomicAdd(&hist[(unsigned)(cand[i] >> 52)], 1u);
        __syncthreads();
        find_threshold(hist, wsum, &sh_lb2, tid, NDET);
        unsigned lb2 = sh_lb2;          // lb2 >= lb, count(keys >= lb2) >= NDET
        // --- compact keys >= lb2 into cbuf ---
        for (int i = tid; i < (int)cnt; i += K2_TPB) {
            unsigned long long k64 = cand[i];
            if ((unsigned)(k64 >> 32) >= lb2) {
                unsigned pos = atomicAdd(&sh_n2, 1u);
                if (pos < 2048) cbuf[pos] = k64;
            }
        }
        __syncthreads();
        unsigned cnt2 = sh_n2;
        if (cnt2 <= 2048) {             // expected path (ties pathologies excluded)
            cnt = cnt2;
            n = 128; while (n < (int)cnt) n <<= 1;
            for (int i = tid; i < n; i += K2_TPB)
                cand[i] = (i < (int)cnt) ? cbuf[i] : 0ULL;
            __syncthreads();
        } else {
            n = 128; while (n < (int)cnt) n <<= 1;
            for (int i = tid; i < n; i += K2_TPB) if (i >= (int)cnt) cand[i] = 0ULL;
            __syncthreads();
        }
    } else {
        n = 128;
        for (int i = tid; i < n; i += K2_TPB) if (i >= (int)cnt) cand[i] = 0ULL;
        __syncthreads();
    }

    // --- ascending bitonic sort of n keys; top-100 at n-1 .. n-100 ---
    for (int k = 2; k <= n; k <<= 1) {
        for (int j = k >> 1; j > 0; j >>= 1) {
            for (int i = tid; i < n; i += K2_TPB) {
                int ixj = i ^ j;
                if (ixj > i) {
                    bool up = ((i & k) == 0);
                    unsigned long long a = cand[i], b = cand[ixj];
                    if ((a > b) == up) { cand[i] = b; cand[ixj] = a; }
                }
            }
            __syncthreads();
        }
    }

    // --- decode + clip + normalize top-100 boxes; record feature rows ---
    if (tid < NDET) {
        unsigned long long key = cand[n - 1 - tid];
        unsigned e = 0xFFFFFFFFu - (unsigned)(key & 0xFFFFFFFFull);
        int pr = e / NFG, cm = e - pr * NFG, c = cm + 1;
        long long rw = (long long)img * P + pr;
        float x1 = props[rw * 4 + 0], y1 = props[rw * 4 + 1];
        float x2 = props[rw * 4 + 2], y2 = props[rw * 4 + 3];
        float w = x2 - x1, hgt = y2 - y1;
        float cx = x1 + 0.5f * w, cy = y1 + 0.5f * hgt;
        const float* rr = reg + rw * (4 * NCLS) + 4 * c;
        float dx = rr[0] / 10.0f, dy = rr[1] / 10.0f;
        float dw = fminf(rr[2] / 5.0f, BBOX_CLIP);
        float dh = fminf(rr[3] / 5.0f, BBOX_CLIP);
        float pcx = dx * w + cx, pcy = dy * hgt + cy;
        float pw_ = expf(dw) * w, ph_ = expf(dh) * hgt;
        float bx1 = pcx - 0.5f * pw_, by1 = pcy - 0.5f * ph_;
        float bx2 = pcx + 0.5f * pw_, by2 = pcy + 0.5f * ph_;
        float W = (float)(*pW), H = (float)(*pH);
        bx1 = fminf(fmaxf(bx1, 0.0f), W);
        bx2 = fminf(fmaxf(bx2, 0.0f), W);
        by1 = fminf(fmaxf(by1, 0.0f), H);
        by2 = fminf(fmaxf(by2, 0.0f), H);
        int o = (img * NDET + tid) * 4;
        outBoxes[o + 0] = bx1 / H;
        outBoxes[o + 1] = by1 / H;
        outBoxes[o + 2] = bx2 / H;
        outBoxes[o + 3] = by2 / H;
        keepRow[img * NDET + tid] = (unsigned)rw;
    }
}

// ---------------- K3: feature gather (1 det per block, float4) ----------------
__global__ __launch_bounds__(256) void k3_feats(
        const float* __restrict__ feats, const unsigned* __restrict__ keepRow,
        float* __restrict__ outF) {
    int det = blockIdx.x;
    long long r = keepRow[det];
    const float4* src = (const float4*)(feats + r * FDIM);
    float4* dst = (float4*)(outF + (long long)det * FDIM);
    dst[threadIdx.x] = src[threadIdx.x];
}

extern "C" void kernel_launch(void* const* d_in, const int* in_sizes, int n_in,
                              void* d_out, int out_size, void* d_ws, size_t ws_size,
                              hipStream_t stream) {
    const float* logits = (const float*)d_in[0];
    const float* reg    = (const float*)d_in[1];
    const float* props  = (const float*)d_in[2];
    const float* feats  = (const float*)d_in[3];
    const int*   pH     = (const int*)d_in[5];
    const int*   pW     = (const int*)d_in[6];

    int N = in_sizes[0] / NCLS;               // total proposals (B*P)
    int B = out_size / (NDET * (4 + FDIM));   // 8
    int P = N / B;

    // workspace: rowoff [N] f32 | maxk [N] u32 | keepRow [B*NDET] u32
    char* ws = (char*)d_ws;
    float*    rowoff  = (float*)ws;
    unsigned* maxk    = (unsigned*)(rowoff + N);
    unsigned* keepRow = (unsigned*)(maxk + N);

    float* outBoxes = (float*)d_out;
    float* outFeats = outBoxes + (size_t)B * NDET * 4;

    k1_soft<<<(N + RPB - 1) / RPB, K1_TPB, 0, stream>>>(logits, rowoff, maxk, N);
    k2_select<<<B, K2_TPB, 0, stream>>>(logits, reg, props, pH, pW,
                                        rowoff, maxk, outBoxes, keepRow, P);
    k3_feats<<<B * NDET, 256, 0, stream>>>(feats, keepRow, outFeats);
}